// Round 2
// baseline (4202.444 us; speedup 1.0000x reference)
//
#include <hip/hip_runtime.h>

// Problem constants (B=64, C=D=64, H=W=64, K=1024)
#define K_CODES 1024
#define D_DIM   64
#define N_ROWS  262144      // B*H*W
#define HW      4096        // H*W
#define CHW     262144      // C*H*W
#define N_ELEM  16777216    // B*C*H*W
#define DECAY   0.99f
#define OMD     0.01f       // 1 - DECAY
#define EPS_F   1e-05f
#define MARGIN  0.03f       // ~10x worst-case fp32 distance error
#define FLAG_CAP 32768

// Workspace layout (bytes)
constexpr size_t OFF_COUNTS  = 0;        // 1024 floats
constexpr size_t OFF_DW      = 4096;     // 65536 floats (ends 266240)
constexpr size_t OFF_LOSS    = 266240;   // 1 double
constexpr size_t OFF_FLAGCNT = 266248;   // 1 int (+4 pad)
constexpr size_t ZERO_BYTES  = 266256;   // memset [0, ZERO_BYTES)
constexpr size_t OFF_W2      = 266256;   // 1024 floats
constexpr size_t OFF_NEWW    = 270352;   // 65536 floats
constexpr size_t OFF_IDX     = 532496;   // 262144 ints
constexpr size_t OFF_FLAGS   = 1581072;  // FLAG_CAP ints (ends 1712144)

__global__ __launch_bounds__(256) void w2_kernel(const float* __restrict__ w,
                                                 float* __restrict__ w2) {
    int k = blockIdx.x * 256 + threadIdx.x;
    if (k < K_CODES) {
        const float* wk = w + k * D_DIM;
        float s = 0.f;
#pragma unroll
        for (int d = 0; d < D_DIM; ++d) s = fmaf(wk[d], wk[d], s);
        w2[k] = s;
    }
}

// One thread per row, fp32 scan. Weights read via wave-uniform scalar loads.
// Rows whose best-vs-runner-up margin is below MARGIN get flagged for fp64
// refinement (near-ties where fp32 rounding could flip the argmin).
__global__ __launch_bounds__(256, 4) void argmin_kernel(
    const float* __restrict__ inp, const float* __restrict__ weight,
    const float* __restrict__ w2, int* __restrict__ idx_ws,
    float* __restrict__ out_idx_f, float* __restrict__ counts,
    float* __restrict__ dw, int* __restrict__ flagcnt,
    int* __restrict__ flaglist) {
    int row = blockIdx.x * 256 + threadIdx.x;
    int b  = row >> 12;          // row / (H*W)
    int hw = row & (HW - 1);
    const float* xp = inp + (size_t)b * CHW + hw;

    float x[D_DIM];
#pragma unroll
    for (int d = 0; d < D_DIM; ++d) x[d] = xp[(size_t)d * HW];

    float x2 = 0.f;
#pragma unroll
    for (int d = 0; d < D_DIM; ++d) x2 = fmaf(x[d], x[d], x2);

    float best = 3.4e38f, best2 = 3.4e38f;
    int bk = 0;
    for (int k = 0; k < K_CODES; ++k) {
        const float* wk = weight + k * D_DIM;  // uniform address -> s_load
        float d0 = 0.f, d1 = 0.f, d2 = 0.f, d3 = 0.f;
#pragma unroll
        for (int d = 0; d < D_DIM; d += 4) {
            d0 = fmaf(wk[d + 0], x[d + 0], d0);
            d1 = fmaf(wk[d + 1], x[d + 1], d1);
            d2 = fmaf(wk[d + 2], x[d + 2], d2);
            d3 = fmaf(wk[d + 3], x[d + 3], d3);
        }
        float dot  = (d0 + d1) + (d2 + d3);
        float dist = (x2 + w2[k]) - 2.0f * dot;
        if (dist < best) { best2 = best; best = dist; bk = k; }
        else if (dist < best2) { best2 = dist; }
    }

    idx_ws[row]    = bk;
    out_idx_f[row] = (float)bk;

    if (best2 - best < MARGIN) {
        int pos = atomicAdd(flagcnt, 1);
        if (pos < FLAG_CAP) flaglist[pos] = row;
    }

    atomicAdd(&counts[bk], 1.0f);
    float* dwk = dw + bk * D_DIM;
#pragma unroll
    for (int d = 0; d < D_DIM; ++d) atomicAdd(&dwk[d], x[d]);
}

// fp64 rescan of flagged rows (true argmin); patch idx/counts/dw on change.
__global__ __launch_bounds__(256) void refine_kernel(
    const float* __restrict__ inp, const float* __restrict__ weight,
    int* __restrict__ idx_ws, float* __restrict__ out_idx_f,
    float* __restrict__ counts, float* __restrict__ dw,
    const int* __restrict__ flagcnt, const int* __restrict__ flaglist) {
    int cnt = *flagcnt;
    if (cnt > FLAG_CAP) cnt = FLAG_CAP;

    __shared__ float  sx[D_DIM];
    __shared__ double sdist[256];
    __shared__ int    sidx[256];
    int t = threadIdx.x;

    for (int r = blockIdx.x; r < cnt; r += gridDim.x) {
        int row = flaglist[r];
        int b  = row >> 12;
        int hw = row & (HW - 1);
        const float* xp = inp + (size_t)b * CHW + hw;

        if (t < D_DIM) sx[t] = xp[(size_t)t * HW];
        __syncthreads();

        double x2 = 0.0;
#pragma unroll
        for (int d = 0; d < D_DIM; ++d) {
            double xv = (double)sx[d];
            x2 += xv * xv;
        }

        double bestd = 1.0e300;
        int besti = 0;
#pragma unroll
        for (int j = 0; j < 4; ++j) {
            int k = t + j * 256;
            const float* wk = weight + k * D_DIM;
            double dot = 0.0, w2 = 0.0;
#pragma unroll
            for (int d = 0; d < D_DIM; ++d) {
                double wv = (double)wk[d];
                dot += wv * (double)sx[d];
                w2  += wv * wv;
            }
            double dist = (x2 + w2) - 2.0 * dot;
            if (dist < bestd) { bestd = dist; besti = k; }
        }
        sdist[t] = bestd;
        sidx[t]  = besti;
        __syncthreads();
        for (int s = 128; s > 0; s >>= 1) {
            if (t < s) {
                double od = sdist[t + s];
                int    oi = sidx[t + s];
                if (od < sdist[t] || (od == sdist[t] && oi < sidx[t])) {
                    sdist[t] = od; sidx[t] = oi;
                }
            }
            __syncthreads();
        }

        int nb = sidx[0];
        int ob = idx_ws[row];
        if (nb != ob) {
            if (t == 0) {
                idx_ws[row]    = nb;
                out_idx_f[row] = (float)nb;
                atomicAdd(&counts[ob], -1.0f);
                atomicAdd(&counts[nb],  1.0f);
            }
            if (t < D_DIM) {
                float xv = sx[t];
                atomicAdd(&dw[ob * D_DIM + t], -xv);
                atomicAdd(&dw[nb * D_DIM + t],  xv);
            }
        }
        __syncthreads();
    }
}

// Single block: EMA decay, Laplace smoothing, new_weight = ew / cs
__global__ __launch_bounds__(1024) void ema_kernel(
    const float* __restrict__ ema_cs, const float* __restrict__ ema_w,
    const float* __restrict__ counts, const float* __restrict__ dw,
    float* __restrict__ new_w) {
    __shared__ float red[K_CODES];
    __shared__ float csbuf[K_CODES];
    int k = threadIdx.x;

    float cs = ema_cs[k] * DECAY + OMD * counts[k];
    red[k] = cs;
    __syncthreads();
    for (int s = 512; s > 0; s >>= 1) {
        if (k < s) red[k] += red[k + s];
        __syncthreads();
    }
    float n = red[0];

    float csm = (cs + EPS_F) / (n + (float)K_CODES * EPS_F) * n;
    csbuf[k] = csm;
    __syncthreads();

    for (int i = k; i < K_CODES * D_DIM; i += 1024) {
        new_w[i] = (ema_w[i] * DECAY + OMD * dw[i]) / csbuf[i >> 6];
    }
}

// Gather updated codebook, straight-through output, commitment-loss partials.
__global__ __launch_bounds__(256) void out_kernel(
    const float* __restrict__ inp, const float* __restrict__ new_w,
    const int* __restrict__ idx_ws, float* __restrict__ out,
    double* __restrict__ loss_acc) {
    int row = blockIdx.x * 256 + threadIdx.x;
    int b  = row >> 12;
    int hw = row & (HW - 1);
    const float* xp = inp + (size_t)b * CHW + hw;
    float* op = out + 1 + (size_t)b * CHW + hw;  // out[0] is the loss scalar

    int k = idx_ws[row];
    const float* q = new_w + k * D_DIM;

    float lsum = 0.f;
#pragma unroll
    for (int d = 0; d < D_DIM; ++d) {
        float xv = xp[(size_t)d * HW];
        float qv = q[d];
        float diff = qv - xv;            // stop_gradient(quantized) - x
        lsum = fmaf(diff, diff, lsum);
        op[(size_t)d * HW] = xv + diff;  // x + (quantized - x)
    }

    __shared__ double lred[256];
    lred[threadIdx.x] = (double)lsum;
    __syncthreads();
    for (int s = 128; s > 0; s >>= 1) {
        if (threadIdx.x < s) lred[threadIdx.x] += lred[threadIdx.x + s];
        __syncthreads();
    }
    if (threadIdx.x == 0) atomicAdd(loss_acc, lred[0]);
}

__global__ void loss_final(const double* __restrict__ loss_acc,
                           float* __restrict__ out) {
    out[0] = (float)(0.25 * (*loss_acc / (double)N_ELEM));
}

extern "C" void kernel_launch(void* const* d_in, const int* in_sizes, int n_in,
                              void* d_out, int out_size, void* d_ws, size_t ws_size,
                              hipStream_t stream) {
    const float* inp    = (const float*)d_in[0];
    const float* weight = (const float*)d_in[1];
    const float* ema_cs = (const float*)d_in[2];
    const float* ema_w  = (const float*)d_in[3];
    float* out = (float*)d_out;

    char* ws = (char*)d_ws;
    float*  counts   = (float*)(ws + OFF_COUNTS);
    float*  dw       = (float*)(ws + OFF_DW);
    double* loss_acc = (double*)(ws + OFF_LOSS);
    int*    flagcnt  = (int*)(ws + OFF_FLAGCNT);
    float*  w2       = (float*)(ws + OFF_W2);
    float*  new_w    = (float*)(ws + OFF_NEWW);
    int*    idx_ws   = (int*)(ws + OFF_IDX);
    int*    flaglist = (int*)(ws + OFF_FLAGS);

    float* out_idx_f = out + 1 + (size_t)N_ELEM;

    hipMemsetAsync(ws, 0, ZERO_BYTES, stream);  // counts + dw + loss + flagcnt

    w2_kernel<<<(K_CODES + 255) / 256, 256, 0, stream>>>(weight, w2);

    argmin_kernel<<<N_ROWS / 256, 256, 0, stream>>>(
        inp, weight, w2, idx_ws, out_idx_f, counts, dw, flagcnt, flaglist);

    refine_kernel<<<256, 256, 0, stream>>>(
        inp, weight, idx_ws, out_idx_f, counts, dw, flagcnt, flaglist);

    ema_kernel<<<1, 1024, 0, stream>>>(ema_cs, ema_w, counts, dw, new_w);

    out_kernel<<<N_ROWS / 256, 256, 0, stream>>>(inp, new_w, idx_ws, out, loss_acc);

    loss_final<<<1, 1, 0, stream>>>(loss_acc, out);
}

// Round 3
// 1332.891 us; speedup vs baseline: 3.1529x; 3.1529x over previous
//
#include <hip/hip_runtime.h>

// Problem constants (B=64, C=D=64, H=W=64, K=1024)
#define K_CODES 1024
#define D_DIM   64
#define N_ROWS  262144      // B*H*W
#define HW      4096        // H*W
#define CHW     262144      // C*H*W
#define N_ELEM  16777216    // B*C*H*W
#define DECAY   0.99f
#define OMD     0.01f       // 1 - DECAY
#define EPS_F   1e-05f
#define MARGIN  0.03f       // ~10x worst-case fp32 distance error
#define FLAG_CAP 32768
#define LIST_CAP 2048       // per-code row-list cap (mean 256, sd 16)

// Workspace layout (bytes); [0,64) is the only zeroed region
constexpr size_t OFF_LOSS    = 0;        // 1 double
constexpr size_t OFF_FLAGCNT = 8;        // 1 int
constexpr size_t ZERO_BYTES  = 64;
constexpr size_t OFF_W2      = 64;       // 1024 f
constexpr size_t OFF_COUNTS  = 4160;     // 1024 f
constexpr size_t OFF_DW      = 8256;     // 65536 f
constexpr size_t OFF_NEWW    = 270400;   // 65536 f
constexpr size_t OFF_IDX     = 532544;   // 262144 i
constexpr size_t OFF_FLAGS   = 1581120;  // FLAG_CAP i (ends 1712192)

__global__ __launch_bounds__(256) void w2_kernel(const float* __restrict__ w,
                                                 float* __restrict__ w2) {
    int k = blockIdx.x * 256 + threadIdx.x;
    if (k < K_CODES) {
        const float* wk = w + k * D_DIM;
        float s = 0.f;
#pragma unroll
        for (int d = 0; d < D_DIM; ++d) s = fmaf(wk[d], wk[d], s);
        w2[k] = s;
    }
}

// One thread per row, fp32 scan. xm = -2*x held in VGPRs (waves_per_eu(4,4)
// gives a 128-VGPR budget so the compiler has no reason to rematerialize).
// Weights/w2 are wave-uniform -> scalar loads. Near-ties flagged for fp64.
__global__ __launch_bounds__(256)
__attribute__((amdgpu_waves_per_eu(4, 4)))
void argmin_kernel(const float* __restrict__ inp, const float* __restrict__ weight,
                   const float* __restrict__ w2, int* __restrict__ idx_ws,
                   float* __restrict__ out_idx_f,
                   int* __restrict__ flagcnt, int* __restrict__ flaglist) {
    int row = blockIdx.x * 256 + threadIdx.x;
    int b  = row >> 12;
    int hw = row & (HW - 1);
    const float* xp = inp + (size_t)b * CHW + hw;

    float xm[D_DIM];
#pragma unroll
    for (int d = 0; d < D_DIM; ++d) xm[d] = -2.0f * xp[(size_t)d * HW];

    // val(k) = w2[k] - 2*dot(x,w_k) = dist(k) - |x|^2 (same ordering/margins)
    float best = 3.4e38f, best2 = 3.4e38f;
    int bk = 0;
    for (int k = 0; k < K_CODES; ++k) {
        const float* wk = weight + k * D_DIM;  // uniform address -> s_load
        float d0 = 0.f, d1 = 0.f, d2 = 0.f, d3 = 0.f;
#pragma unroll
        for (int d = 0; d < D_DIM; d += 4) {
            d0 = fmaf(wk[d + 0], xm[d + 0], d0);
            d1 = fmaf(wk[d + 1], xm[d + 1], d1);
            d2 = fmaf(wk[d + 2], xm[d + 2], d2);
            d3 = fmaf(wk[d + 3], xm[d + 3], d3);
        }
        float val = w2[k] + ((d0 + d1) + (d2 + d3));
        bool lt = val < best;
        best2 = lt ? best : fminf(best2, val);
        best  = lt ? val : best;
        bk    = lt ? k : bk;
    }

    idx_ws[row]    = bk;
    out_idx_f[row] = (float)bk;

    if (best2 - best < MARGIN) {
        int pos = atomicAdd(flagcnt, 1);
        if (pos < FLAG_CAP) flaglist[pos] = row;
    }
}

// fp64 rescan of flagged rows; patch idx/out_idx_f only (runs BEFORE dw).
__global__ __launch_bounds__(256) void refine_kernel(
    const float* __restrict__ inp, const float* __restrict__ weight,
    int* __restrict__ idx_ws, float* __restrict__ out_idx_f,
    const int* __restrict__ flagcnt, const int* __restrict__ flaglist) {
    int cnt = *flagcnt;
    if (cnt > FLAG_CAP) cnt = FLAG_CAP;

    __shared__ float  sx[D_DIM];
    __shared__ double sdist[256];
    __shared__ int    sidx[256];
    int t = threadIdx.x;

    for (int r = blockIdx.x; r < cnt; r += gridDim.x) {
        int row = flaglist[r];
        int b  = row >> 12;
        int hw = row & (HW - 1);
        const float* xp = inp + (size_t)b * CHW + hw;

        if (t < D_DIM) sx[t] = xp[(size_t)t * HW];
        __syncthreads();

        double x2 = 0.0;
#pragma unroll
        for (int d = 0; d < D_DIM; ++d) {
            double xv = (double)sx[d];
            x2 += xv * xv;
        }

        double bestd = 1.0e300;
        int besti = 0;
#pragma unroll
        for (int j = 0; j < 4; ++j) {
            int k = t + j * 256;
            const float* wk = weight + k * D_DIM;
            double dot = 0.0, w2 = 0.0;
#pragma unroll
            for (int d = 0; d < D_DIM; ++d) {
                double wv = (double)wk[d];
                dot += wv * (double)sx[d];
                w2  += wv * wv;
            }
            double dist = (x2 + w2) - 2.0 * dot;
            if (dist < bestd) { bestd = dist; besti = k; }
        }
        sdist[t] = bestd;
        sidx[t]  = besti;
        __syncthreads();
        for (int s = 128; s > 0; s >>= 1) {
            if (t < s) {
                double od = sdist[t + s];
                int    oi = sidx[t + s];
                if (od < sdist[t] || (od == sdist[t] && oi < sidx[t])) {
                    sdist[t] = od; sidx[t] = oi;
                }
            }
            __syncthreads();
        }

        if (t == 0) {
            int nb = sidx[0];
            if (nb != idx_ws[row]) {
                idx_ws[row]    = nb;
                out_idx_f[row] = (float)nb;
            }
        }
        __syncthreads();
    }
}

// Owner-computes segment sum: block g owns codes {2g, 2g+1}. Zero atomics to
// global memory. Phase 1: scan idx (L2-resident, 1 MB) building LDS row
// lists. Phase 2: gather x rows (lane = dim, wave-uniform row -> broadcast),
// per-thread register accumulate, LDS tree, direct store of dw + counts.
__global__ __launch_bounds__(256) void dw_kernel(
    const float* __restrict__ inp, const int* __restrict__ idx_ws,
    float* __restrict__ counts, float* __restrict__ dw) {
    __shared__ int   list[2][LIST_CAP];
    __shared__ int   lcnt[2];
    __shared__ float red[256];
    int t = threadIdx.x;
    int g = blockIdx.x;

    if (t < 2) lcnt[t] = 0;
    __syncthreads();

    const int4* idx4 = (const int4*)idx_ws;
    for (int i = t; i < N_ROWS / 4; i += 256) {
        int4 c4 = idx4[i];
        int rbase = i * 4;
#pragma unroll
        for (int j = 0; j < 4; ++j) {
            int c = (&c4.x)[j];
            if ((c >> 1) == g) {
                int slot = c & 1;
                int pos = atomicAdd(&lcnt[slot], 1);  // LDS atomic
                if (pos < LIST_CAP) list[slot][pos] = rbase + j;
            }
        }
    }
    __syncthreads();

    int d   = t & 63;
    int sub = t >> 6;
#pragma unroll
    for (int c = 0; c < 2; ++c) {
        int cnt = lcnt[c];
        int cc  = cnt > LIST_CAP ? LIST_CAP : cnt;
        float acc = 0.f;
        for (int i = sub; i < cc; i += 4) {
            int row = list[c][i];  // wave-uniform -> LDS broadcast
            acc += inp[(size_t)(row >> 12) * CHW + (size_t)d * HW + (row & (HW - 1))];
        }
        red[t] = acc;
        __syncthreads();
        if (t < 64) {
            dw[(2 * g + c) * D_DIM + t] =
                red[t] + red[t + 64] + red[t + 128] + red[t + 192];
        }
        if (t == 0) counts[2 * g + c] = (float)cnt;
        __syncthreads();
    }
}

// Single block: EMA decay, Laplace smoothing, new_weight = ew / cs
__global__ __launch_bounds__(1024) void ema_kernel(
    const float* __restrict__ ema_cs, const float* __restrict__ ema_w,
    const float* __restrict__ counts, const float* __restrict__ dw,
    float* __restrict__ new_w) {
    __shared__ float red[K_CODES];
    __shared__ float csbuf[K_CODES];
    int k = threadIdx.x;

    float cs = ema_cs[k] * DECAY + OMD * counts[k];
    red[k] = cs;
    __syncthreads();
    for (int s = 512; s > 0; s >>= 1) {
        if (k < s) red[k] += red[k + s];
        __syncthreads();
    }
    float n = red[0];

    float csm = (cs + EPS_F) / (n + (float)K_CODES * EPS_F) * n;
    csbuf[k] = csm;
    __syncthreads();

    for (int i = k; i < K_CODES * D_DIM; i += 1024) {
        new_w[i] = (ema_w[i] * DECAY + OMD * dw[i]) / csbuf[i >> 6];
    }
}

// Gather updated codebook, straight-through output, commitment-loss partials.
__global__ __launch_bounds__(256) void out_kernel(
    const float* __restrict__ inp, const float* __restrict__ new_w,
    const int* __restrict__ idx_ws, float* __restrict__ out,
    double* __restrict__ loss_acc) {
    int row = blockIdx.x * 256 + threadIdx.x;
    int b  = row >> 12;
    int hw = row & (HW - 1);
    const float* xp = inp + (size_t)b * CHW + hw;
    float* op = out + 1 + (size_t)b * CHW + hw;  // out[0] is the loss scalar

    int k = idx_ws[row];
    const float* q = new_w + k * D_DIM;

    float lsum = 0.f;
#pragma unroll
    for (int d = 0; d < D_DIM; ++d) {
        float xv = xp[(size_t)d * HW];
        float qv = q[d];
        float diff = qv - xv;            // stop_gradient(quantized) - x
        lsum = fmaf(diff, diff, lsum);
        op[(size_t)d * HW] = xv + diff;  // x + (quantized - x)
    }

    __shared__ double lred[256];
    lred[threadIdx.x] = (double)lsum;
    __syncthreads();
    for (int s = 128; s > 0; s >>= 1) {
        if (threadIdx.x < s) lred[threadIdx.x] += lred[threadIdx.x + s];
        __syncthreads();
    }
    if (threadIdx.x == 0) atomicAdd(loss_acc, lred[0]);
}

__global__ void loss_final(const double* __restrict__ loss_acc,
                           float* __restrict__ out) {
    out[0] = (float)(0.25 * (*loss_acc / (double)N_ELEM));
}

extern "C" void kernel_launch(void* const* d_in, const int* in_sizes, int n_in,
                              void* d_out, int out_size, void* d_ws, size_t ws_size,
                              hipStream_t stream) {
    const float* inp    = (const float*)d_in[0];
    const float* weight = (const float*)d_in[1];
    const float* ema_cs = (const float*)d_in[2];
    const float* ema_w  = (const float*)d_in[3];
    float* out = (float*)d_out;

    char* ws = (char*)d_ws;
    double* loss_acc = (double*)(ws + OFF_LOSS);
    int*    flagcnt  = (int*)(ws + OFF_FLAGCNT);
    float*  w2       = (float*)(ws + OFF_W2);
    float*  counts   = (float*)(ws + OFF_COUNTS);
    float*  dw       = (float*)(ws + OFF_DW);
    float*  new_w    = (float*)(ws + OFF_NEWW);
    int*    idx_ws   = (int*)(ws + OFF_IDX);
    int*    flaglist = (int*)(ws + OFF_FLAGS);

    float* out_idx_f = out + 1 + (size_t)N_ELEM;

    hipMemsetAsync(ws, 0, ZERO_BYTES, stream);  // loss + flagcnt only

    w2_kernel<<<(K_CODES + 255) / 256, 256, 0, stream>>>(weight, w2);

    argmin_kernel<<<N_ROWS / 256, 256, 0, stream>>>(
        inp, weight, w2, idx_ws, out_idx_f, flagcnt, flaglist);

    refine_kernel<<<256, 256, 0, stream>>>(
        inp, weight, idx_ws, out_idx_f, flagcnt, flaglist);

    dw_kernel<<<K_CODES / 2, 256, 0, stream>>>(inp, idx_ws, counts, dw);

    ema_kernel<<<1, 1024, 0, stream>>>(ema_cs, ema_w, counts, dw, new_w);

    out_kernel<<<N_ROWS / 256, 256, 0, stream>>>(inp, new_w, idx_ws, out, loss_acc);

    loss_final<<<1, 1, 0, stream>>>(loss_acc, out);
}

// Round 5
// 836.763 us; speedup vs baseline: 5.0223x; 1.5929x over previous
//
#include <hip/hip_runtime.h>

// Problem constants (B=64, C=D=64, H=W=64, K=1024)
#define K_CODES 1024
#define D_DIM   64
#define N_ROWS  262144      // B*H*W
#define HW      4096        // H*W
#define CHW     262144      // C*H*W
#define N_ELEM  16777216    // B*C*H*W
#define DECAY   0.99f
#define OMD     0.01f       // 1 - DECAY
#define EPS_F   1e-05f
#define MARGIN_BF 0.006f    // ~40 sigma of split-bf16 score noise (~1e-4)
#define FLAG_CAP 32768      // expected flags ~400 (0.15%): 80x headroom
#define LIST_CAP 2048       // per-code row-list cap (mean 256, sd 16)

typedef __attribute__((ext_vector_type(8))) short bf16x8;  // 8 bf16 = 4 VGPRs
typedef __attribute__((ext_vector_type(4))) float f32x4;

// Workspace layout (bytes); [0,64) is the only zeroed region. All 16B-aligned.
constexpr size_t OFF_LOSS    = 0;        // 1 double
constexpr size_t OFF_FLAGCNT = 8;        // 1 int
constexpr size_t ZERO_BYTES  = 64;
constexpr size_t OFF_W2F     = 64;       // 1024 f   -> 4160
constexpr size_t OFF_W2D     = 4160;     // 1024 d   -> 12352
constexpr size_t OFF_CS      = 12352;    // 1024 f   -> 16448
constexpr size_t OFF_COUNTS  = 16448;    // 1024 f   -> 20544
constexpr size_t OFF_DW      = 20544;    // 65536 f  -> 282688
constexpr size_t OFF_NEWW    = 282688;   // 65536 f  -> 544832
constexpr size_t OFF_IDX     = 544832;   // 262144 i -> 1593408
constexpr size_t OFF_FLAGS   = 1593408;  // 32768 i  -> 1724480
constexpr size_t OFF_WFRAG   = 1724480;  // 131072 bf16 (hi+lo, 262144 B) -> 1986624

__device__ __forceinline__ short f2bf(float f) {  // RNE float->bf16
    unsigned u = __float_as_uint(f);
    u += 0x7fffu + ((u >> 16) & 1u);
    return (short)(u >> 16);
}
__device__ __forceinline__ float bf2f(short h) {
    return __uint_as_float(((unsigned)(unsigned short)h) << 16);
}

// One-time prep: W swizzled to bf16 hi/lo B-fragment pairs for 16x16x32 MFMA.
// Fragment layout: frag index f = ((j*2+h)*2+p)*64 + L holds, for p=0 (hi) /
// p=1 (lo), W[j*16+(L&15)][h*32+(L>>4)*8 .. +8). Also w2 in f32 + f64.
__global__ __launch_bounds__(256) void prep_kernel(
    const float* __restrict__ w, short* __restrict__ wfrag,
    float* __restrict__ w2f, double* __restrict__ w2d) {
    int t = threadIdx.x;
    if (blockIdx.x < 32) {
        int gid = blockIdx.x * 256 + t;  // (j<<7)|(h<<6)|L
        int j = gid >> 7, h = (gid >> 6) & 1, L = gid & 63;
        int code = j * 16 + (L & 15);
        int kb = h * 32 + ((L >> 4) << 3);
        const float* wp = w + code * D_DIM + kb;
        short hi[8], lo[8];
#pragma unroll
        for (int i = 0; i < 8; ++i) {
            float v = wp[i];
            short hb = f2bf(v);
            hi[i] = hb;
            lo[i] = f2bf(v - bf2f(hb));
        }
        short* dh = wfrag + (size_t)(((j * 2 + h) * 2 + 0) * 64 + L) * 8;
        short* dl = wfrag + (size_t)(((j * 2 + h) * 2 + 1) * 64 + L) * 8;
#pragma unroll
        for (int i = 0; i < 8; ++i) { dh[i] = hi[i]; dl[i] = lo[i]; }
    } else {
        int k = (blockIdx.x - 32) * 256 + t;
        const float* wk = w + k * D_DIM;
        float sf = 0.f; double sd = 0.0;
#pragma unroll
        for (int d = 0; d < D_DIM; ++d) {
            float wv = wk[d];
            sf = fmaf(wv, wv, sf);
            sd = fma((double)wv, (double)wv, sd);
        }
        w2f[k] = sf; w2d[k] = sd;
    }
}

// Split-bf16 MFMA argmin: block = 4 waves = 64 rows. dot = xh*wh + xh*wl +
// xl*wh (xl*wl ~2^-18 dropped) -> score noise ~1e-4; near-ties (<0.006)
// flagged for fp64 refine. W fragments staged per-supertile through LDS so
// all 4 waves share one global read stream. Also emits xt = x in row-major
// [row][64] (into the quantized output region, used by refine/dw, then
// overwritten by out_kernel).
__global__ __launch_bounds__(256) void argmin_kernel(
    const float* __restrict__ inp, const short* __restrict__ wfrag,
    const float* __restrict__ w2f, int* __restrict__ idx_ws,
    float* __restrict__ out_idx_f, float* __restrict__ xt,
    int* __restrict__ flagcnt, int* __restrict__ flaglist) {
    __shared__ alignas(16) float xs[64][68];   // +4 pad
    __shared__ float w2s[K_CODES];
    __shared__ alignas(16) short wtile[8192];  // 16 KB: 4 j-tiles x (2h x hi/lo)
    int t = threadIdx.x;
    ((float4*)w2s)[t] = ((const float4*)w2f)[t];

    int rowbase = blockIdx.x * 64;
    int b = rowbase >> 12, hwb = rowbase & (HW - 1);
    const float* xp = inp + (size_t)b * CHW + hwb;
    int lane = t & 63, wave = t >> 6;
#pragma unroll
    for (int it = 0; it < 16; ++it) {
        int d = wave * 16 + it;
        xs[lane][d] = xp[(size_t)d * HW + lane];  // coalesced 256B per d
    }
    __syncthreads();

    // xt side-product: coalesced row-major dump of this block's 64 rows
    float4* xt4 = (float4*)(xt + (size_t)rowbase * D_DIM);
#pragma unroll
    for (int i2 = 0; i2 < 4; ++i2) {
        int c2 = t + i2 * 256;
        xt4[c2] = ((const float4*)xs[c2 >> 4])[c2 & 15];
    }

    int q = lane >> 4, col = lane & 15;
    int rl = wave * 16 + col;  // A-fragment row m = lane&15
    bf16x8 ah0, ah1, al0, al1;
#pragma unroll
    for (int i = 0; i < 8; ++i) {
        float v0 = xs[rl][q * 8 + i];         // k = quad*8+i
        short h0 = f2bf(v0);
        ah0[i] = h0; al0[i] = f2bf(v0 - bf2f(h0));
        float v1 = xs[rl][q * 8 + 32 + i];    // k-half 1
        short h1 = f2bf(v1);
        ah1[i] = h1; al1[i] = f2bf(v1 - bf2f(h1));
    }

    float best[4]  = {3.4e38f, 3.4e38f, 3.4e38f, 3.4e38f};
    float best2[4] = {3.4e38f, 3.4e38f, 3.4e38f, 3.4e38f};
    int   bk[4]    = {0, 0, 0, 0};
    const float4* wsrc = (const float4*)wfrag;

    for (int st = 0; st < 16; ++st) {
        float4 stg[4];
#pragma unroll
        for (int i2 = 0; i2 < 4; ++i2) stg[i2] = wsrc[st * 1024 + t + i2 * 256];
        __syncthreads();  // previous tile's LDS reads done
        float4* dst = (float4*)wtile;
#pragma unroll
        for (int i2 = 0; i2 < 4; ++i2) dst[t + i2 * 256] = stg[i2];
        __syncthreads();

#pragma unroll
        for (int jj = 0; jj < 4; ++jj) {
            int j = st * 4 + jj;
            const bf16x8* wt = (const bf16x8*)wtile;
            bf16x8 bh0 = wt[(jj * 4 + 0) * 64 + lane];
            bf16x8 bl0 = wt[(jj * 4 + 1) * 64 + lane];
            bf16x8 bh1 = wt[(jj * 4 + 2) * 64 + lane];
            bf16x8 bl1 = wt[(jj * 4 + 3) * 64 + lane];
            f32x4 acc = {0.f, 0.f, 0.f, 0.f};
            acc = __builtin_amdgcn_mfma_f32_16x16x32_bf16(al0, bh0, acc, 0, 0, 0);
            acc = __builtin_amdgcn_mfma_f32_16x16x32_bf16(al1, bh1, acc, 0, 0, 0);
            acc = __builtin_amdgcn_mfma_f32_16x16x32_bf16(ah0, bl0, acc, 0, 0, 0);
            acc = __builtin_amdgcn_mfma_f32_16x16x32_bf16(ah1, bl1, acc, 0, 0, 0);
            acc = __builtin_amdgcn_mfma_f32_16x16x32_bf16(ah0, bh0, acc, 0, 0, 0);
            acc = __builtin_amdgcn_mfma_f32_16x16x32_bf16(ah1, bh1, acc, 0, 0, 0);
            float w2c = w2s[j * 16 + col];
            int c = j * 16 + col;
#pragma unroll
            for (int r = 0; r < 4; ++r) {
                float s = fmaf(-2.f, acc[r], w2c);
                bool lt = s < best[r];
                best2[r] = fminf(best2[r], fmaxf(s, best[r]));
                best[r]  = fminf(best[r], s);
                bk[r]    = lt ? c : bk[r];
            }
        }
    }

    // reduce (best,best2,bk) across the 16 column-lanes of each quad-group
#pragma unroll
    for (int m = 1; m < 16; m <<= 1) {
#pragma unroll
        for (int r = 0; r < 4; ++r) {
            float ob  = __shfl_xor(best[r], m, 64);
            float ob2 = __shfl_xor(best2[r], m, 64);
            int   obk = __shfl_xor(bk[r], m, 64);
            float nb2 = fminf(fminf(best2[r], ob2), fmaxf(best[r], ob));
            int   nbk = ob < best[r] ? obk
                        : (best[r] < ob ? bk[r] : min(bk[r], obk));
            best[r]  = fminf(best[r], ob);
            best2[r] = nb2;
            bk[r]    = nbk;
        }
    }

    if (col == 0) {
#pragma unroll
        for (int r = 0; r < 4; ++r) {
            int row = rowbase + wave * 16 + q * 4 + r;  // C row = quad*4+reg
            idx_ws[row]    = bk[r];
            out_idx_f[row] = (float)bk[r];
            if (best2[r] - best[r] < MARGIN_BF) {
                int pos = atomicAdd(flagcnt, 1);
                if (pos < FLAG_CAP) flaglist[pos] = row;
            }
        }
    }
}

// fp64 rescan of flagged rows (exact); patches idx/out_idx_f before dw/out.
__global__ __launch_bounds__(256) void refine_kernel(
    const float* __restrict__ xt, const float* __restrict__ weight,
    const double* __restrict__ w2d, int* __restrict__ idx_ws,
    float* __restrict__ out_idx_f, const int* __restrict__ flagcnt,
    const int* __restrict__ flaglist) {
    int cnt = *flagcnt;
    if (cnt > FLAG_CAP) cnt = FLAG_CAP;

    __shared__ float  sx[D_DIM];
    __shared__ double sd[256];
    __shared__ int    si[256];
    int t = threadIdx.x;

    for (int r = blockIdx.x; r < cnt; r += gridDim.x) {
        int row = flaglist[r];
        if (t < D_DIM) sx[t] = xt[(size_t)row * D_DIM + t];
        __syncthreads();

        double x2 = 0.0;
#pragma unroll
        for (int d = 0; d < D_DIM; ++d) {
            double xv = (double)sx[d];
            x2 = fma(xv, xv, x2);
        }

        double bd = 1.0e300; int bi = 0;
#pragma unroll
        for (int jj = 0; jj < 4; ++jj) {
            int k = t + jj * 256;
            const float* wk = weight + k * D_DIM;
            double dot = 0.0;
#pragma unroll
            for (int d = 0; d < D_DIM; ++d)
                dot = fma((double)wk[d], (double)sx[d], dot);
            double dist = (x2 + w2d[k]) - 2.0 * dot;
            if (dist < bd) { bd = dist; bi = k; }
        }
        sd[t] = bd; si[t] = bi;
        __syncthreads();
        for (int s = 128; s > 0; s >>= 1) {
            if (t < s) {
                double od = sd[t + s]; int oi = si[t + s];
                if (od < sd[t] || (od == sd[t] && oi < si[t])) {
                    sd[t] = od; si[t] = oi;
                }
            }
            __syncthreads();
        }
        if (t == 0 && si[0] != idx_ws[row]) {
            idx_ws[row]    = si[0];
            out_idx_f[row] = (float)si[0];
        }
        __syncthreads();
    }
}

// Owner-computes segment sum (zero global atomics): block g owns codes 2g,2g+1.
// Phase 2 reads xt row-major: 64 lanes x 4B = one 256B segment per row.
__global__ __launch_bounds__(256) void dw_kernel(
    const float* __restrict__ xt, const int* __restrict__ idx_ws,
    float* __restrict__ counts, float* __restrict__ dw) {
    __shared__ int   list[2][LIST_CAP];
    __shared__ int   lcnt[2];
    __shared__ float red[256];
    int t = threadIdx.x;
    int g = blockIdx.x;

    if (t < 2) lcnt[t] = 0;
    __syncthreads();

    const int4* idx4 = (const int4*)idx_ws;
    for (int i = t; i < N_ROWS / 4; i += 256) {
        int4 c4 = idx4[i];
        int rbase = i * 4;
#pragma unroll
        for (int j = 0; j < 4; ++j) {
            int c = (&c4.x)[j];
            if ((c >> 1) == g) {
                int slot = c & 1;
                int pos = atomicAdd(&lcnt[slot], 1);  // LDS atomic
                if (pos < LIST_CAP) list[slot][pos] = rbase + j;
            }
        }
    }
    __syncthreads();

    int d   = t & 63;
    int sub = t >> 6;
#pragma unroll
    for (int c = 0; c < 2; ++c) {
        int cnt = lcnt[c];
        int cc  = cnt > LIST_CAP ? LIST_CAP : cnt;
        float acc = 0.f;
        for (int i = sub; i < cc; i += 4) {
            int row = list[c][i];  // wave-uniform -> LDS broadcast
            acc += xt[(size_t)row * D_DIM + d];  // coalesced 256B
        }
        red[t] = acc;
        __syncthreads();
        if (t < 64) {
            dw[(2 * g + c) * D_DIM + t] =
                red[t] + red[t + 64] + red[t + 128] + red[t + 192];
        }
        if (t == 0) counts[2 * g + c] = (float)cnt;
        __syncthreads();
    }
}

// Laplace-smoothed cluster sizes (single block, tiny)
__global__ __launch_bounds__(1024) void csn_kernel(
    const float* __restrict__ ema_cs, const float* __restrict__ counts,
    float* __restrict__ csbuf) {
    __shared__ float red[K_CODES];
    int k = threadIdx.x;
    float cs = ema_cs[k] * DECAY + OMD * counts[k];
    red[k] = cs;
    __syncthreads();
    for (int s = 512; s > 0; s >>= 1) {
        if (k < s) red[k] += red[k + s];
        __syncthreads();
    }
    float n = red[0];
    csbuf[k] = (cs + EPS_F) / (n + (float)K_CODES * EPS_F) * n;
}

// new_w = (ema_w*decay + (1-decay)*dw) / csbuf
__global__ __launch_bounds__(256) void emaw_kernel(
    const float* __restrict__ ema_w, const float* __restrict__ dw,
    const float* __restrict__ csbuf, float* __restrict__ new_w) {
    int i = blockIdx.x * 256 + threadIdx.x;
    new_w[i] = (ema_w[i] * DECAY + OMD * dw[i]) / csbuf[i >> 6];
}

// Gather updated codebook, straight-through output, commitment-loss partials.
// Reads inp (NCHW) and overwrites the quantized region (which held xt).
__global__ __launch_bounds__(256) void out_kernel(
    const float* __restrict__ inp, const float* __restrict__ new_w,
    const int* __restrict__ idx_ws, float* __restrict__ out,
    double* __restrict__ loss_acc) {
    int row = blockIdx.x * 256 + threadIdx.x;
    int b  = row >> 12;
    int hw = row & (HW - 1);
    const float* xp = inp + (size_t)b * CHW + hw;
    float* op = out + 1 + (size_t)b * CHW + hw;  // out[0] is the loss scalar

    int k = idx_ws[row];
    const float* q = new_w + k * D_DIM;

    float lsum = 0.f;
#pragma unroll
    for (int d = 0; d < D_DIM; ++d) {
        float xv = xp[(size_t)d * HW];
        float qv = q[d];
        float diff = qv - xv;            // stop_gradient(quantized) - x
        lsum = fmaf(diff, diff, lsum);
        op[(size_t)d * HW] = xv + diff;  // x + (quantized - x)
    }

    __shared__ double lred[256];
    lred[threadIdx.x] = (double)lsum;
    __syncthreads();
    for (int s = 128; s > 0; s >>= 1) {
        if (threadIdx.x < s) lred[threadIdx.x] += lred[threadIdx.x + s];
        __syncthreads();
    }
    if (threadIdx.x == 0) atomicAdd(loss_acc, lred[0]);
}

__global__ void loss_final(const double* __restrict__ loss_acc,
                           float* __restrict__ out) {
    out[0] = (float)(0.25 * (*loss_acc / (double)N_ELEM));
}

extern "C" void kernel_launch(void* const* d_in, const int* in_sizes, int n_in,
                              void* d_out, int out_size, void* d_ws, size_t ws_size,
                              hipStream_t stream) {
    const float* inp    = (const float*)d_in[0];
    const float* weight = (const float*)d_in[1];
    const float* ema_cs = (const float*)d_in[2];
    const float* ema_w  = (const float*)d_in[3];
    float* out = (float*)d_out;

    char* ws = (char*)d_ws;
    double* loss_acc = (double*)(ws + OFF_LOSS);
    int*    flagcnt  = (int*)(ws + OFF_FLAGCNT);
    float*  w2f      = (float*)(ws + OFF_W2F);
    double* w2d      = (double*)(ws + OFF_W2D);
    float*  csbuf    = (float*)(ws + OFF_CS);
    float*  counts   = (float*)(ws + OFF_COUNTS);
    float*  dw       = (float*)(ws + OFF_DW);
    float*  new_w    = (float*)(ws + OFF_NEWW);
    int*    idx_ws   = (int*)(ws + OFF_IDX);
    int*    flaglist = (int*)(ws + OFF_FLAGS);
    short*  wfrag    = (short*)(ws + OFF_WFRAG);

    float* xt        = out + 1;               // scratch: overwritten by out_kernel
    float* out_idx_f = out + 1 + (size_t)N_ELEM;

    hipMemsetAsync(ws, 0, ZERO_BYTES, stream);  // loss + flagcnt only

    prep_kernel<<<36, 256, 0, stream>>>(weight, wfrag, w2f, w2d);

    argmin_kernel<<<N_ROWS / 64, 256, 0, stream>>>(
        inp, wfrag, w2f, idx_ws, out_idx_f, xt, flagcnt, flaglist);

    refine_kernel<<<1024, 256, 0, stream>>>(
        xt, weight, w2d, idx_ws, out_idx_f, flagcnt, flaglist);

    dw_kernel<<<K_CODES / 2, 256, 0, stream>>>(xt, idx_ws, counts, dw);

    csn_kernel<<<1, 1024, 0, stream>>>(ema_cs, counts, csbuf);

    emaw_kernel<<<K_CODES * D_DIM / 256, 256, 0, stream>>>(ema_w, dw, csbuf, new_w);

    out_kernel<<<N_ROWS / 256, 256, 0, stream>>>(inp, new_w, idx_ws, out, loss_acc);

    loss_final<<<1, 1, 0, stream>>>(loss_acc, out);
}

// Round 6
// 621.317 us; speedup vs baseline: 6.7638x; 1.3468x over previous
//
#include <hip/hip_runtime.h>

// Problem constants (B=64, C=D=64, H=W=64, K=1024)
#define K_CODES 1024
#define D_DIM   64
#define N_ROWS  262144      // B*H*W
#define HW      4096        // H*W
#define CHW     262144      // C*H*W
#define N_ELEM  16777216    // B*C*H*W
#define DECAY   0.99f
#define OMD     0.01f       // 1 - DECAY
#define EPS_F   1e-05f
#define MARGIN_BF 0.006f    // ~40 sigma of split-bf16 score noise (~1e-4)
#define FLAG_CAP 32768      // expected flags ~400 (0.15%)
#define SEG_CAP  2048       // per-code row cap (mean 256, Poisson max ~340)
#define NHB      64         // hist blocks (4096 rows each)

typedef __attribute__((ext_vector_type(8))) short bf16x8;  // 8 bf16 = 4 VGPRs
typedef __attribute__((ext_vector_type(4))) float f32x4;

// Workspace layout (bytes); [0,64) is the only zeroed region. All 16B-aligned.
// FLAGS and WFRAG temporally overlay SORT (dead before scatter writes it).
constexpr size_t OFF_LOSS    = 0;        // 1 double
constexpr size_t OFF_FLAGCNT = 8;        // 1 int
constexpr size_t ZERO_BYTES  = 64;
constexpr size_t OFF_W2F     = 64;       // 1024 f   -> 4160
constexpr size_t OFF_W2D     = 4160;     // 1024 d   -> 12352
constexpr size_t OFF_CS      = 12352;    // 1024 f   -> 16448
constexpr size_t OFF_GOFF    = 16448;    // 1025 i   -> 20608 (padded)
constexpr size_t OFF_DW      = 20608;    // 65536 f  -> 282752
constexpr size_t OFF_NEWW    = 282752;   // 65536 f  -> 544896
constexpr size_t OFF_IDX     = 544896;   // 262144 i -> 1593472
constexpr size_t OFF_HISTB   = 1593472;  // 64x1024 i -> 1855616
constexpr size_t OFF_SORT    = 1855616;  // 262144 i -> 2904192
constexpr size_t OFF_FLAGS   = 1855616;  // 32768 i (dead after refine)
constexpr size_t OFF_WFRAG   = 1986688;  // 131072 bf16 (dead after argmin) -> 2248832

__device__ __forceinline__ short f2bf(float f) {  // RNE float->bf16
    unsigned u = __float_as_uint(f);
    u += 0x7fffu + ((u >> 16) & 1u);
    return (short)(u >> 16);
}
__device__ __forceinline__ float bf2f(short h) {
    return __uint_as_float(((unsigned)(unsigned short)h) << 16);
}

// One-time prep: W swizzled to bf16 hi/lo B-fragment pairs for 16x16x32 MFMA.
__global__ __launch_bounds__(256) void prep_kernel(
    const float* __restrict__ w, short* __restrict__ wfrag,
    float* __restrict__ w2f, double* __restrict__ w2d) {
    int t = threadIdx.x;
    if (blockIdx.x < 32) {
        int gid = blockIdx.x * 256 + t;  // (j<<7)|(h<<6)|L
        int j = gid >> 7, h = (gid >> 6) & 1, L = gid & 63;
        int code = j * 16 + (L & 15);
        int kb = h * 32 + ((L >> 4) << 3);
        const float* wp = w + code * D_DIM + kb;
        short hi[8], lo[8];
#pragma unroll
        for (int i = 0; i < 8; ++i) {
            float v = wp[i];
            short hb = f2bf(v);
            hi[i] = hb;
            lo[i] = f2bf(v - bf2f(hb));
        }
        short* dh = wfrag + (size_t)(((j * 2 + h) * 2 + 0) * 64 + L) * 8;
        short* dl = wfrag + (size_t)(((j * 2 + h) * 2 + 1) * 64 + L) * 8;
#pragma unroll
        for (int i = 0; i < 8; ++i) { dh[i] = hi[i]; dl[i] = lo[i]; }
    } else {
        int k = (blockIdx.x - 32) * 256 + t;
        const float* wk = w + k * D_DIM;
        float sf = 0.f; double sd = 0.0;
#pragma unroll
        for (int d = 0; d < D_DIM; ++d) {
            float wv = wk[d];
            sf = fmaf(wv, wv, sf);
            sd = fma((double)wv, (double)wv, sd);
        }
        w2f[k] = sf; w2d[k] = sd;
    }
}

// Split-bf16 MFMA argmin: block = 4 waves = 64 rows; near-ties flagged for
// fp64 refine. W fragments staged per-supertile through LDS. Also emits
// xt = x row-major [row][64] into the quantized output region (scratch).
__global__ __launch_bounds__(256) void argmin_kernel(
    const float* __restrict__ inp, const short* __restrict__ wfrag,
    const float* __restrict__ w2f, int* __restrict__ idx_ws,
    float* __restrict__ out_idx_f, float* __restrict__ xt,
    int* __restrict__ flagcnt, int* __restrict__ flaglist) {
    __shared__ alignas(16) float xs[64][68];   // +4 pad
    __shared__ float w2s[K_CODES];
    __shared__ alignas(16) short wtile[8192];  // 16 KB: 4 j-tiles x (2h x hi/lo)
    int t = threadIdx.x;
    ((float4*)w2s)[t] = ((const float4*)w2f)[t];

    int rowbase = blockIdx.x * 64;
    int b = rowbase >> 12, hwb = rowbase & (HW - 1);
    const float* xp = inp + (size_t)b * CHW + hwb;
    int lane = t & 63, wave = t >> 6;
#pragma unroll
    for (int it = 0; it < 16; ++it) {
        int d = wave * 16 + it;
        xs[lane][d] = xp[(size_t)d * HW + lane];  // coalesced 256B per d
    }
    __syncthreads();

    // xt side-product: coalesced row-major dump of this block's 64 rows
    float4* xt4 = (float4*)(xt + (size_t)rowbase * D_DIM);
#pragma unroll
    for (int i2 = 0; i2 < 4; ++i2) {
        int c2 = t + i2 * 256;
        xt4[c2] = ((const float4*)xs[c2 >> 4])[c2 & 15];
    }

    int q = lane >> 4, col = lane & 15;
    int rl = wave * 16 + col;  // A-fragment row m = lane&15
    bf16x8 ah0, ah1, al0, al1;
#pragma unroll
    for (int i = 0; i < 8; ++i) {
        float v0 = xs[rl][q * 8 + i];
        short h0 = f2bf(v0);
        ah0[i] = h0; al0[i] = f2bf(v0 - bf2f(h0));
        float v1 = xs[rl][q * 8 + 32 + i];
        short h1 = f2bf(v1);
        ah1[i] = h1; al1[i] = f2bf(v1 - bf2f(h1));
    }

    float best[4]  = {3.4e38f, 3.4e38f, 3.4e38f, 3.4e38f};
    float best2[4] = {3.4e38f, 3.4e38f, 3.4e38f, 3.4e38f};
    int   bk[4]    = {0, 0, 0, 0};
    const float4* wsrc = (const float4*)wfrag;

    for (int st = 0; st < 16; ++st) {
        float4 stg[4];
#pragma unroll
        for (int i2 = 0; i2 < 4; ++i2) stg[i2] = wsrc[st * 1024 + t + i2 * 256];
        __syncthreads();  // previous tile's LDS reads done
        float4* dst = (float4*)wtile;
#pragma unroll
        for (int i2 = 0; i2 < 4; ++i2) dst[t + i2 * 256] = stg[i2];
        __syncthreads();

#pragma unroll
        for (int jj = 0; jj < 4; ++jj) {
            int j = st * 4 + jj;
            const bf16x8* wt = (const bf16x8*)wtile;
            bf16x8 bh0 = wt[(jj * 4 + 0) * 64 + lane];
            bf16x8 bl0 = wt[(jj * 4 + 1) * 64 + lane];
            bf16x8 bh1 = wt[(jj * 4 + 2) * 64 + lane];
            bf16x8 bl1 = wt[(jj * 4 + 3) * 64 + lane];
            f32x4 acc = {0.f, 0.f, 0.f, 0.f};
            acc = __builtin_amdgcn_mfma_f32_16x16x32_bf16(al0, bh0, acc, 0, 0, 0);
            acc = __builtin_amdgcn_mfma_f32_16x16x32_bf16(al1, bh1, acc, 0, 0, 0);
            acc = __builtin_amdgcn_mfma_f32_16x16x32_bf16(ah0, bl0, acc, 0, 0, 0);
            acc = __builtin_amdgcn_mfma_f32_16x16x32_bf16(ah1, bl1, acc, 0, 0, 0);
            acc = __builtin_amdgcn_mfma_f32_16x16x32_bf16(ah0, bh0, acc, 0, 0, 0);
            acc = __builtin_amdgcn_mfma_f32_16x16x32_bf16(ah1, bh1, acc, 0, 0, 0);
            float w2c = w2s[j * 16 + col];
            int c = j * 16 + col;
#pragma unroll
            for (int r = 0; r < 4; ++r) {
                float s = fmaf(-2.f, acc[r], w2c);
                bool lt = s < best[r];
                best2[r] = fminf(best2[r], fmaxf(s, best[r]));
                best[r]  = fminf(best[r], s);
                bk[r]    = lt ? c : bk[r];
            }
        }
    }

#pragma unroll
    for (int m = 1; m < 16; m <<= 1) {
#pragma unroll
        for (int r = 0; r < 4; ++r) {
            float ob  = __shfl_xor(best[r], m, 64);
            float ob2 = __shfl_xor(best2[r], m, 64);
            int   obk = __shfl_xor(bk[r], m, 64);
            float nb2 = fminf(fminf(best2[r], ob2), fmaxf(best[r], ob));
            int   nbk = ob < best[r] ? obk
                        : (best[r] < ob ? bk[r] : min(bk[r], obk));
            best[r]  = fminf(best[r], ob);
            best2[r] = nb2;
            bk[r]    = nbk;
        }
    }

    if (col == 0) {
#pragma unroll
        for (int r = 0; r < 4; ++r) {
            int row = rowbase + wave * 16 + q * 4 + r;  // C row = quad*4+reg
            idx_ws[row]    = bk[r];
            out_idx_f[row] = (float)bk[r];
            if (best2[r] - best[r] < MARGIN_BF) {
                int pos = atomicAdd(flagcnt, 1);
                if (pos < FLAG_CAP) flaglist[pos] = row;
            }
        }
    }
}

// fp64 rescan of flagged rows (exact); patches idx/out_idx_f before hist.
__global__ __launch_bounds__(256) void refine_kernel(
    const float* __restrict__ xt, const float* __restrict__ weight,
    const double* __restrict__ w2d, int* __restrict__ idx_ws,
    float* __restrict__ out_idx_f, const int* __restrict__ flagcnt,
    const int* __restrict__ flaglist) {
    int cnt = *flagcnt;
    if (cnt > FLAG_CAP) cnt = FLAG_CAP;

    __shared__ float  sx[D_DIM];
    __shared__ double sd[256];
    __shared__ int    si[256];
    int t = threadIdx.x;

    for (int r = blockIdx.x; r < cnt; r += gridDim.x) {
        int row = flaglist[r];
        if (t < D_DIM) sx[t] = xt[(size_t)row * D_DIM + t];
        __syncthreads();

        double x2 = 0.0;
#pragma unroll
        for (int d = 0; d < D_DIM; ++d) {
            double xv = (double)sx[d];
            x2 = fma(xv, xv, x2);
        }

        double bd = 1.0e300; int bi = 0;
#pragma unroll
        for (int jj = 0; jj < 4; ++jj) {
            int k = t + jj * 256;
            const float* wk = weight + k * D_DIM;
            double dot = 0.0;
#pragma unroll
            for (int d = 0; d < D_DIM; ++d)
                dot = fma((double)wk[d], (double)sx[d], dot);
            double dist = (x2 + w2d[k]) - 2.0 * dot;
            if (dist < bd) { bd = dist; bi = k; }
        }
        sd[t] = bd; si[t] = bi;
        __syncthreads();
        for (int s = 128; s > 0; s >>= 1) {
            if (t < s) {
                double od = sd[t + s]; int oi = si[t + s];
                if (od < sd[t] || (od == sd[t] && oi < si[t])) {
                    sd[t] = od; si[t] = oi;
                }
            }
            __syncthreads();
        }
        if (t == 0 && si[0] != idx_ws[row]) {
            idx_ws[row]    = si[0];
            out_idx_f[row] = (float)si[0];
        }
        __syncthreads();
    }
}

// Counting sort, pass 1: per-block LDS histogram of 4096 rows -> histb[b][k].
__global__ __launch_bounds__(256) void hist_kernel(
    const int* __restrict__ idx_ws, int* __restrict__ histb) {
    __shared__ int h[K_CODES];
    int t = threadIdx.x, b = blockIdx.x;
    for (int i = t; i < K_CODES; i += 256) h[i] = 0;
    __syncthreads();
    const int4* idx4 = (const int4*)idx_ws + b * 1024;
#pragma unroll
    for (int i = 0; i < 4; ++i) {
        int4 c = idx4[t + i * 256];
        atomicAdd(&h[c.x], 1); atomicAdd(&h[c.y], 1);
        atomicAdd(&h[c.z], 1); atomicAdd(&h[c.w], 1);
    }
    __syncthreads();
    for (int i = t; i < K_CODES; i += 256) histb[b * K_CODES + i] = h[i];
}

// Pass 2 (1 block, 1024 thr): column prefix over block histograms + global
// exclusive prefix -> cursors (in histb) + goff. Fused Laplace/csn.
__global__ __launch_bounds__(1024) void scan_kernel(
    int* __restrict__ histb, int* __restrict__ goff,
    const float* __restrict__ ema_cs, float* __restrict__ csbuf) {
    __shared__ int pre[K_CODES];
    __shared__ float red[K_CODES];
    int k = threadIdx.x;

    int s = 0;
    for (int b = 0; b < NHB; ++b) {
        int v = histb[b * K_CODES + k];
        histb[b * K_CODES + k] = s;  // local exclusive prefix
        s += v;
    }
    int cnt = s;

    pre[k] = cnt;
    __syncthreads();
    for (int d = 1; d < K_CODES; d <<= 1) {
        int v = (k >= d) ? pre[k - d] : 0;
        __syncthreads();
        if (k >= d) pre[k] += v;
        __syncthreads();
    }
    int base = pre[k] - cnt;
    goff[k] = base;
    if (k == K_CODES - 1) goff[K_CODES] = pre[k];

    for (int b = 0; b < NHB; ++b) histb[b * K_CODES + k] += base;

    float cs = ema_cs[k] * DECAY + OMD * (float)cnt;
    red[k] = cs;
    __syncthreads();
    for (int s2 = 512; s2 > 0; s2 >>= 1) {
        if (k < s2) red[k] += red[k + s2];
        __syncthreads();
    }
    float n = red[0];
    csbuf[k] = (cs + EPS_F) / (n + (float)K_CODES * EPS_F) * n;
}

// Pass 3: scatter row ids into code-sorted order via LDS cursors.
__global__ __launch_bounds__(256) void scatter_kernel(
    const int* __restrict__ idx_ws, const int* __restrict__ histb,
    int* __restrict__ sorted) {
    __shared__ int cur[K_CODES];
    int t = threadIdx.x, b = blockIdx.x;
    for (int i = t; i < K_CODES; i += 256) cur[i] = histb[b * K_CODES + i];
    __syncthreads();
    const int4* idx4 = (const int4*)idx_ws + b * 1024;
#pragma unroll
    for (int i = 0; i < 4; ++i) {
        int4 c = idx4[t + i * 256];
        int r0 = (b * 1024 + t + i * 256) * 4;
        sorted[atomicAdd(&cur[c.x], 1)] = r0 + 0;
        sorted[atomicAdd(&cur[c.y], 1)] = r0 + 1;
        sorted[atomicAdd(&cur[c.z], 1)] = r0 + 2;
        sorted[atomicAdd(&cur[c.w], 1)] = r0 + 3;
    }
}

// Pass 4: one block per code; gather xt rows (coalesced 256B), 2 chains for
// load ILP, LDS tree, direct dw store. Zero global atomics.
__global__ __launch_bounds__(256) void dwred_kernel(
    const float* __restrict__ xt, const int* __restrict__ sorted,
    const int* __restrict__ goff, float* __restrict__ dw) {
    __shared__ int   rows[SEG_CAP];
    __shared__ float red[256];
    int k = blockIdx.x, t = threadIdx.x;
    int base = goff[k];
    int cnt = goff[k + 1] - base;
    int cc = cnt > SEG_CAP ? SEG_CAP : cnt;

    for (int i = t; i < cc; i += 256) rows[i] = sorted[base + i];
    __syncthreads();

    int d = t & 63, sub = t >> 6;
    float a0 = 0.f, a1 = 0.f;
    int i = sub;
    for (; i + 4 < cc; i += 8) {
        a0 += xt[(size_t)rows[i] * D_DIM + d];
        a1 += xt[(size_t)rows[i + 4] * D_DIM + d];
    }
    for (; i < cc; i += 4) a0 += xt[(size_t)rows[i] * D_DIM + d];
    red[t] = a0 + a1;
    __syncthreads();
    if (t < 64) {
        dw[k * D_DIM + t] = red[t] + red[t + 64] + red[t + 128] + red[t + 192];
    }
}

// new_w = (ema_w*decay + (1-decay)*dw) / csbuf
__global__ __launch_bounds__(256) void emaw_kernel(
    const float* __restrict__ ema_w, const float* __restrict__ dw,
    const float* __restrict__ csbuf, float* __restrict__ new_w) {
    int i = blockIdx.x * 256 + threadIdx.x;
    new_w[i] = (ema_w[i] * DECAY + OMD * dw[i]) / csbuf[i >> 6];
}

// Gather updated codebook, straight-through output, commitment-loss partials.
__global__ __launch_bounds__(256) void out_kernel(
    const float* __restrict__ inp, const float* __restrict__ new_w,
    const int* __restrict__ idx_ws, float* __restrict__ out,
    double* __restrict__ loss_acc) {
    int row = blockIdx.x * 256 + threadIdx.x;
    int b  = row >> 12;
    int hw = row & (HW - 1);
    const float* xp = inp + (size_t)b * CHW + hw;
    float* op = out + 1 + (size_t)b * CHW + hw;  // out[0] is the loss scalar

    int k = idx_ws[row];
    const float* q = new_w + k * D_DIM;

    float lsum = 0.f;
#pragma unroll
    for (int d = 0; d < D_DIM; ++d) {
        float xv = xp[(size_t)d * HW];
        float qv = q[d];
        float diff = qv - xv;            // stop_gradient(quantized) - x
        lsum = fmaf(diff, diff, lsum);
        op[(size_t)d * HW] = xv + diff;  // x + (quantized - x)
    }

    __shared__ double lred[256];
    lred[threadIdx.x] = (double)lsum;
    __syncthreads();
    for (int s = 128; s > 0; s >>= 1) {
        if (threadIdx.x < s) lred[threadIdx.x] += lred[threadIdx.x + s];
        __syncthreads();
    }
    if (threadIdx.x == 0) atomicAdd(loss_acc, lred[0]);
}

__global__ void loss_final(const double* __restrict__ loss_acc,
                           float* __restrict__ out) {
    out[0] = (float)(0.25 * (*loss_acc / (double)N_ELEM));
}

extern "C" void kernel_launch(void* const* d_in, const int* in_sizes, int n_in,
                              void* d_out, int out_size, void* d_ws, size_t ws_size,
                              hipStream_t stream) {
    const float* inp    = (const float*)d_in[0];
    const float* weight = (const float*)d_in[1];
    const float* ema_cs = (const float*)d_in[2];
    const float* ema_w  = (const float*)d_in[3];
    float* out = (float*)d_out;

    char* ws = (char*)d_ws;
    double* loss_acc = (double*)(ws + OFF_LOSS);
    int*    flagcnt  = (int*)(ws + OFF_FLAGCNT);
    float*  w2f      = (float*)(ws + OFF_W2F);
    double* w2d      = (double*)(ws + OFF_W2D);
    float*  csbuf    = (float*)(ws + OFF_CS);
    int*    goff     = (int*)(ws + OFF_GOFF);
    float*  dw       = (float*)(ws + OFF_DW);
    float*  new_w    = (float*)(ws + OFF_NEWW);
    int*    idx_ws   = (int*)(ws + OFF_IDX);
    int*    histb    = (int*)(ws + OFF_HISTB);
    int*    sorted   = (int*)(ws + OFF_SORT);
    int*    flaglist = (int*)(ws + OFF_FLAGS);
    short*  wfrag    = (short*)(ws + OFF_WFRAG);

    float* xt        = out + 1;               // scratch: overwritten by out_kernel
    float* out_idx_f = out + 1 + (size_t)N_ELEM;

    hipMemsetAsync(ws, 0, ZERO_BYTES, stream);  // loss + flagcnt only

    prep_kernel<<<36, 256, 0, stream>>>(weight, wfrag, w2f, w2d);

    argmin_kernel<<<N_ROWS / 64, 256, 0, stream>>>(
        inp, wfrag, w2f, idx_ws, out_idx_f, xt, flagcnt, flaglist);

    refine_kernel<<<1024, 256, 0, stream>>>(
        xt, weight, w2d, idx_ws, out_idx_f, flagcnt, flaglist);

    hist_kernel<<<NHB, 256, 0, stream>>>(idx_ws, histb);

    scan_kernel<<<1, 1024, 0, stream>>>(histb, goff, ema_cs, csbuf);

    scatter_kernel<<<NHB, 256, 0, stream>>>(idx_ws, histb, sorted);

    dwred_kernel<<<K_CODES, 256, 0, stream>>>(xt, sorted, goff, dw);

    emaw_kernel<<<K_CODES * D_DIM / 256, 256, 0, stream>>>(ema_w, dw, csbuf, new_w);

    out_kernel<<<N_ROWS / 256, 256, 0, stream>>>(inp, new_w, idx_ws, out, loss_acc);

    loss_final<<<1, 1, 0, stream>>>(loss_acc, out);
}

// Round 7
// 618.489 us; speedup vs baseline: 6.7947x; 1.0046x over previous
//
#include <hip/hip_runtime.h>

// Problem constants (B=64, C=D=64, H=W=64, K=1024)
#define K_CODES 1024
#define D_DIM   64
#define N_ROWS  262144      // B*H*W
#define HW      4096        // H*W
#define CHW     262144      // C*H*W
#define N_ELEM  16777216    // B*C*H*W
#define DECAY   0.99f
#define OMD     0.01f       // 1 - DECAY
#define EPS_F   1e-05f
#define MARGIN_BF 0.006f    // ~40 sigma of split-bf16 score noise (~1e-4)
#define FLAG_CAP 32768      // expected flags ~400 (0.15%)
#define SEG_CAP  2048       // per-code row cap (mean 256, Poisson max ~340)
#define NHB      64         // hist blocks (4096 rows each)

typedef __attribute__((ext_vector_type(8))) short bf16x8;  // 8 bf16 = 4 VGPRs
typedef __attribute__((ext_vector_type(4))) float f32x4;

// Workspace layout (bytes); [0,64) is the only zeroed region. All 16B-aligned.
// FLAGS and WFRAG temporally overlay SORT (dead before scatter writes it).
constexpr size_t OFF_LOSS    = 0;        // 1 double
constexpr size_t OFF_FLAGCNT = 8;        // 1 int
constexpr size_t ZERO_BYTES  = 64;
constexpr size_t OFF_W2F     = 64;       // 1024 f   -> 4160
constexpr size_t OFF_W2D     = 4160;     // 1024 d   -> 12352
constexpr size_t OFF_CS      = 12352;    // 1024 f   -> 16448
constexpr size_t OFF_GOFF    = 16448;    // 1025 i   -> 20608 (padded)
constexpr size_t OFF_DW      = 20608;    // 65536 f  -> 282752
constexpr size_t OFF_NEWW    = 282752;   // 65536 f  -> 544896
constexpr size_t OFF_IDX     = 544896;   // 262144 i -> 1593472
constexpr size_t OFF_HISTB   = 1593472;  // 64x1024 i -> 1855616
constexpr size_t OFF_SORT    = 1855616;  // 262144 i -> 2904192
constexpr size_t OFF_FLAGS   = 1855616;  // 32768 i (dead after refine)
constexpr size_t OFF_WFRAG   = 1986688;  // 131072 bf16 (dead after argmin) -> 2248832

__device__ __forceinline__ short f2bf(float f) {  // RNE float->bf16
    unsigned u = __float_as_uint(f);
    u += 0x7fffu + ((u >> 16) & 1u);
    return (short)(u >> 16);
}
__device__ __forceinline__ float bf2f(short h) {
    return __uint_as_float(((unsigned)(unsigned short)h) << 16);
}

// One-time prep: W swizzled to bf16 hi/lo B-fragment pairs for 16x16x32 MFMA.
__global__ __launch_bounds__(256) void prep_kernel(
    const float* __restrict__ w, short* __restrict__ wfrag,
    float* __restrict__ w2f, double* __restrict__ w2d) {
    int t = threadIdx.x;
    if (blockIdx.x < 32) {
        int gid = blockIdx.x * 256 + t;  // (j<<7)|(h<<6)|L
        int j = gid >> 7, h = (gid >> 6) & 1, L = gid & 63;
        int code = j * 16 + (L & 15);
        int kb = h * 32 + ((L >> 4) << 3);
        const float* wp = w + code * D_DIM + kb;
        short hi[8], lo[8];
#pragma unroll
        for (int i = 0; i < 8; ++i) {
            float v = wp[i];
            short hb = f2bf(v);
            hi[i] = hb;
            lo[i] = f2bf(v - bf2f(hb));
        }
        short* dh = wfrag + (size_t)(((j * 2 + h) * 2 + 0) * 64 + L) * 8;
        short* dl = wfrag + (size_t)(((j * 2 + h) * 2 + 1) * 64 + L) * 8;
#pragma unroll
        for (int i = 0; i < 8; ++i) { dh[i] = hi[i]; dl[i] = lo[i]; }
    } else {
        int k = (blockIdx.x - 32) * 256 + t;
        const float* wk = w + k * D_DIM;
        float sf = 0.f; double sd = 0.0;
#pragma unroll
        for (int d = 0; d < D_DIM; ++d) {
            float wv = wk[d];
            sf = fmaf(wv, wv, sf);
            sd = fma((double)wv, (double)wv, sd);
        }
        w2f[k] = sf; w2d[k] = sd;
    }
}

// Split-bf16 MFMA argmin: block = 4 waves = 64 rows; near-ties flagged for
// fp64 refine. W fragments staged per-supertile through LDS. Also emits
// xt = x row-major [row][64] into the quantized output region (scratch).
// launch_bounds(256,2): 256-VGPR budget — the fragment+prefetch state needs
// ~120 VGPRs; the default budget (60) spilled to scratch -> 320 MB of HBM
// spill traffic (R6 WRITE_SIZE 385 MB vs 66 MB expected).
__global__ __launch_bounds__(256, 2) void argmin_kernel(
    const float* __restrict__ inp, const short* __restrict__ wfrag,
    const float* __restrict__ w2f, int* __restrict__ idx_ws,
    float* __restrict__ out_idx_f, float* __restrict__ xt,
    int* __restrict__ flagcnt, int* __restrict__ flaglist) {
    __shared__ alignas(16) float xs[64][68];   // +4 pad
    __shared__ float w2s[K_CODES];
    __shared__ alignas(16) short wtile[8192];  // 16 KB: 4 j-tiles x (2h x hi/lo)
    int t = threadIdx.x;
    ((float4*)w2s)[t] = ((const float4*)w2f)[t];

    int rowbase = blockIdx.x * 64;
    int b = rowbase >> 12, hwb = rowbase & (HW - 1);
    const float* xp = inp + (size_t)b * CHW + hwb;
    int lane = t & 63, wave = t >> 6;
#pragma unroll
    for (int it = 0; it < 16; ++it) {
        int d = wave * 16 + it;
        xs[lane][d] = xp[(size_t)d * HW + lane];  // coalesced 256B per d
    }
    __syncthreads();

    // xt side-product: coalesced row-major dump of this block's 64 rows
    float4* xt4 = (float4*)(xt + (size_t)rowbase * D_DIM);
#pragma unroll
    for (int i2 = 0; i2 < 4; ++i2) {
        int c2 = t + i2 * 256;
        xt4[c2] = ((const float4*)xs[c2 >> 4])[c2 & 15];
    }

    int q = lane >> 4, col = lane & 15;
    int rl = wave * 16 + col;  // A-fragment row m = lane&15
    bf16x8 ah0, ah1, al0, al1;
#pragma unroll
    for (int i = 0; i < 8; ++i) {
        float v0 = xs[rl][q * 8 + i];
        short h0 = f2bf(v0);
        ah0[i] = h0; al0[i] = f2bf(v0 - bf2f(h0));
        float v1 = xs[rl][q * 8 + 32 + i];
        short h1 = f2bf(v1);
        ah1[i] = h1; al1[i] = f2bf(v1 - bf2f(h1));
    }

    float best[4]  = {3.4e38f, 3.4e38f, 3.4e38f, 3.4e38f};
    float best2[4] = {3.4e38f, 3.4e38f, 3.4e38f, 3.4e38f};
    int   bk[4]    = {0, 0, 0, 0};
    const float4* wsrc = (const float4*)wfrag;

    for (int st = 0; st < 16; ++st) {
        float4 stg[4];
#pragma unroll
        for (int i2 = 0; i2 < 4; ++i2) stg[i2] = wsrc[st * 1024 + t + i2 * 256];
        __syncthreads();  // previous tile's LDS reads done
        float4* dst = (float4*)wtile;
#pragma unroll
        for (int i2 = 0; i2 < 4; ++i2) dst[t + i2 * 256] = stg[i2];
        __syncthreads();

#pragma unroll
        for (int jj = 0; jj < 4; ++jj) {
            int j = st * 4 + jj;
            const bf16x8* wt = (const bf16x8*)wtile;
            bf16x8 bh0 = wt[(jj * 4 + 0) * 64 + lane];
            bf16x8 bl0 = wt[(jj * 4 + 1) * 64 + lane];
            bf16x8 bh1 = wt[(jj * 4 + 2) * 64 + lane];
            bf16x8 bl1 = wt[(jj * 4 + 3) * 64 + lane];
            f32x4 acc = {0.f, 0.f, 0.f, 0.f};
            acc = __builtin_amdgcn_mfma_f32_16x16x32_bf16(al0, bh0, acc, 0, 0, 0);
            acc = __builtin_amdgcn_mfma_f32_16x16x32_bf16(al1, bh1, acc, 0, 0, 0);
            acc = __builtin_amdgcn_mfma_f32_16x16x32_bf16(ah0, bl0, acc, 0, 0, 0);
            acc = __builtin_amdgcn_mfma_f32_16x16x32_bf16(ah1, bl1, acc, 0, 0, 0);
            acc = __builtin_amdgcn_mfma_f32_16x16x32_bf16(ah0, bh0, acc, 0, 0, 0);
            acc = __builtin_amdgcn_mfma_f32_16x16x32_bf16(ah1, bh1, acc, 0, 0, 0);
            float w2c = w2s[j * 16 + col];
            int c = j * 16 + col;
#pragma unroll
            for (int r = 0; r < 4; ++r) {
                float s = fmaf(-2.f, acc[r], w2c);
                bool lt = s < best[r];
                best2[r] = fminf(best2[r], fmaxf(s, best[r]));
                best[r]  = fminf(best[r], s);
                bk[r]    = lt ? c : bk[r];
            }
        }
    }

#pragma unroll
    for (int m = 1; m < 16; m <<= 1) {
#pragma unroll
        for (int r = 0; r < 4; ++r) {
            float ob  = __shfl_xor(best[r], m, 64);
            float ob2 = __shfl_xor(best2[r], m, 64);
            int   obk = __shfl_xor(bk[r], m, 64);
            float nb2 = fminf(fminf(best2[r], ob2), fmaxf(best[r], ob));
            int   nbk = ob < best[r] ? obk
                        : (best[r] < ob ? bk[r] : min(bk[r], obk));
            best[r]  = fminf(best[r], ob);
            best2[r] = nb2;
            bk[r]    = nbk;
        }
    }

    if (col == 0) {
#pragma unroll
        for (int r = 0; r < 4; ++r) {
            int row = rowbase + wave * 16 + q * 4 + r;  // C row = quad*4+reg
            idx_ws[row]    = bk[r];
            out_idx_f[row] = (float)bk[r];
            if (best2[r] - best[r] < MARGIN_BF) {
                int pos = atomicAdd(flagcnt, 1);
                if (pos < FLAG_CAP) flaglist[pos] = row;
            }
        }
    }
}

// fp64 rescan of flagged rows (exact); patches idx/out_idx_f before hist.
__global__ __launch_bounds__(256) void refine_kernel(
    const float* __restrict__ xt, const float* __restrict__ weight,
    const double* __restrict__ w2d, int* __restrict__ idx_ws,
    float* __restrict__ out_idx_f, const int* __restrict__ flagcnt,
    const int* __restrict__ flaglist) {
    int cnt = *flagcnt;
    if (cnt > FLAG_CAP) cnt = FLAG_CAP;

    __shared__ float  sx[D_DIM];
    __shared__ double sd[256];
    __shared__ int    si[256];
    int t = threadIdx.x;

    for (int r = blockIdx.x; r < cnt; r += gridDim.x) {
        int row = flaglist[r];
        if (t < D_DIM) sx[t] = xt[(size_t)row * D_DIM + t];
        __syncthreads();

        double x2 = 0.0;
#pragma unroll
        for (int d = 0; d < D_DIM; ++d) {
            double xv = (double)sx[d];
            x2 = fma(xv, xv, x2);
        }

        double bd = 1.0e300; int bi = 0;
#pragma unroll
        for (int jj = 0; jj < 4; ++jj) {
            int k = t + jj * 256;
            const float* wk = weight + k * D_DIM;
            double dot = 0.0;
#pragma unroll
            for (int d = 0; d < D_DIM; ++d)
                dot = fma((double)wk[d], (double)sx[d], dot);
            double dist = (x2 + w2d[k]) - 2.0 * dot;
            if (dist < bd) { bd = dist; bi = k; }
        }
        sd[t] = bd; si[t] = bi;
        __syncthreads();
        for (int s = 128; s > 0; s >>= 1) {
            if (t < s) {
                double od = sd[t + s]; int oi = si[t + s];
                if (od < sd[t] || (od == sd[t] && oi < si[t])) {
                    sd[t] = od; si[t] = oi;
                }
            }
            __syncthreads();
        }
        if (t == 0 && si[0] != idx_ws[row]) {
            idx_ws[row]    = si[0];
            out_idx_f[row] = (float)si[0];
        }
        __syncthreads();
    }
}

// Counting sort, pass 1: per-block LDS histogram of 4096 rows -> histb[b][k].
__global__ __launch_bounds__(256) void hist_kernel(
    const int* __restrict__ idx_ws, int* __restrict__ histb) {
    __shared__ int h[K_CODES];
    int t = threadIdx.x, b = blockIdx.x;
    for (int i = t; i < K_CODES; i += 256) h[i] = 0;
    __syncthreads();
    const int4* idx4 = (const int4*)idx_ws + b * 1024;
#pragma unroll
    for (int i = 0; i < 4; ++i) {
        int4 c = idx4[t + i * 256];
        atomicAdd(&h[c.x], 1); atomicAdd(&h[c.y], 1);
        atomicAdd(&h[c.z], 1); atomicAdd(&h[c.w], 1);
    }
    __syncthreads();
    for (int i = t; i < K_CODES; i += 256) histb[b * K_CODES + i] = h[i];
}

// Pass 2 (1 block, 1024 thr): column prefix over block histograms + global
// exclusive prefix -> cursors (in histb) + goff. Fused Laplace/csn.
__global__ __launch_bounds__(1024) void scan_kernel(
    int* __restrict__ histb, int* __restrict__ goff,
    const float* __restrict__ ema_cs, float* __restrict__ csbuf) {
    __shared__ int pre[K_CODES];
    __shared__ float red[K_CODES];
    int k = threadIdx.x;

    int s = 0;
    for (int b = 0; b < NHB; ++b) {
        int v = histb[b * K_CODES + k];
        histb[b * K_CODES + k] = s;  // local exclusive prefix
        s += v;
    }
    int cnt = s;

    pre[k] = cnt;
    __syncthreads();
    for (int d = 1; d < K_CODES; d <<= 1) {
        int v = (k >= d) ? pre[k - d] : 0;
        __syncthreads();
        if (k >= d) pre[k] += v;
        __syncthreads();
    }
    int base = pre[k] - cnt;
    goff[k] = base;
    if (k == K_CODES - 1) goff[K_CODES] = pre[k];

    for (int b = 0; b < NHB; ++b) histb[b * K_CODES + k] += base;

    float cs = ema_cs[k] * DECAY + OMD * (float)cnt;
    red[k] = cs;
    __syncthreads();
    for (int s2 = 512; s2 > 0; s2 >>= 1) {
        if (k < s2) red[k] += red[k + s2];
        __syncthreads();
    }
    float n = red[0];
    csbuf[k] = (cs + EPS_F) / (n + (float)K_CODES * EPS_F) * n;
}

// Pass 3: scatter row ids into code-sorted order via LDS cursors.
__global__ __launch_bounds__(256) void scatter_kernel(
    const int* __restrict__ idx_ws, const int* __restrict__ histb,
    int* __restrict__ sorted) {
    __shared__ int cur[K_CODES];
    int t = threadIdx.x, b = blockIdx.x;
    for (int i = t; i < K_CODES; i += 256) cur[i] = histb[b * K_CODES + i];
    __syncthreads();
    const int4* idx4 = (const int4*)idx_ws + b * 1024;
#pragma unroll
    for (int i = 0; i < 4; ++i) {
        int4 c = idx4[t + i * 256];
        int r0 = (b * 1024 + t + i * 256) * 4;
        sorted[atomicAdd(&cur[c.x], 1)] = r0 + 0;
        sorted[atomicAdd(&cur[c.y], 1)] = r0 + 1;
        sorted[atomicAdd(&cur[c.z], 1)] = r0 + 2;
        sorted[atomicAdd(&cur[c.w], 1)] = r0 + 3;
    }
}

// Pass 4: one block per code; gather xt rows (coalesced 256B), 2 chains for
// load ILP, LDS tree, direct dw store. Zero global atomics.
__global__ __launch_bounds__(256) void dwred_kernel(
    const float* __restrict__ xt, const int* __restrict__ sorted,
    const int* __restrict__ goff, float* __restrict__ dw) {
    __shared__ int   rows[SEG_CAP];
    __shared__ float red[256];
    int k = blockIdx.x, t = threadIdx.x;
    int base = goff[k];
    int cnt = goff[k + 1] - base;
    int cc = cnt > SEG_CAP ? SEG_CAP : cnt;

    for (int i = t; i < cc; i += 256) rows[i] = sorted[base + i];
    __syncthreads();

    int d = t & 63, sub = t >> 6;
    float a0 = 0.f, a1 = 0.f;
    int i = sub;
    for (; i + 4 < cc; i += 8) {
        a0 += xt[(size_t)rows[i] * D_DIM + d];
        a1 += xt[(size_t)rows[i + 4] * D_DIM + d];
    }
    for (; i < cc; i += 4) a0 += xt[(size_t)rows[i] * D_DIM + d];
    red[t] = a0 + a1;
    __syncthreads();
    if (t < 64) {
        dw[k * D_DIM + t] = red[t] + red[t + 64] + red[t + 128] + red[t + 192];
    }
}

// new_w = (ema_w*decay + (1-decay)*dw) / csbuf
__global__ __launch_bounds__(256) void emaw_kernel(
    const float* __restrict__ ema_w, const float* __restrict__ dw,
    const float* __restrict__ csbuf, float* __restrict__ new_w) {
    int i = blockIdx.x * 256 + threadIdx.x;
    new_w[i] = (ema_w[i] * DECAY + OMD * dw[i]) / csbuf[i >> 6];
}

// Gather updated codebook, straight-through output, commitment-loss partials.
__global__ __launch_bounds__(256) void out_kernel(
    const float* __restrict__ inp, const float* __restrict__ new_w,
    const int* __restrict__ idx_ws, float* __restrict__ out,
    double* __restrict__ loss_acc) {
    int row = blockIdx.x * 256 + threadIdx.x;
    int b  = row >> 12;
    int hw = row & (HW - 1);
    const float* xp = inp + (size_t)b * CHW + hw;
    float* op = out + 1 + (size_t)b * CHW + hw;  // out[0] is the loss scalar

    int k = idx_ws[row];
    const float* q = new_w + k * D_DIM;

    float lsum = 0.f;
#pragma unroll
    for (int d = 0; d < D_DIM; ++d) {
        float xv = xp[(size_t)d * HW];
        float qv = q[d];
        float diff = qv - xv;            // stop_gradient(quantized) - x
        lsum = fmaf(diff, diff, lsum);
        op[(size_t)d * HW] = xv + diff;  // x + (quantized - x)
    }

    __shared__ double lred[256];
    lred[threadIdx.x] = (double)lsum;
    __syncthreads();
    for (int s = 128; s > 0; s >>= 1) {
        if (threadIdx.x < s) lred[threadIdx.x] += lred[threadIdx.x + s];
        __syncthreads();
    }
    if (threadIdx.x == 0) atomicAdd(loss_acc, lred[0]);
}

__global__ void loss_final(const double* __restrict__ loss_acc,
                           float* __restrict__ out) {
    out[0] = (float)(0.25 * (*loss_acc / (double)N_ELEM));
}

extern "C" void kernel_launch(void* const* d_in, const int* in_sizes, int n_in,
                              void* d_out, int out_size, void* d_ws, size_t ws_size,
                              hipStream_t stream) {
    const float* inp    = (const float*)d_in[0];
    const float* weight = (const float*)d_in[1];
    const float* ema_cs = (const float*)d_in[2];
    const float* ema_w  = (const float*)d_in[3];
    float* out = (float*)d_out;

    char* ws = (char*)d_ws;
    double* loss_acc = (double*)(ws + OFF_LOSS);
    int*    flagcnt  = (int*)(ws + OFF_FLAGCNT);
    float*  w2f      = (float*)(ws + OFF_W2F);
    double* w2d      = (double*)(ws + OFF_W2D);
    float*  csbuf    = (float*)(ws + OFF_CS);
    int*    goff     = (int*)(ws + OFF_GOFF);
    float*  dw       = (float*)(ws + OFF_DW);
    float*  new_w    = (float*)(ws + OFF_NEWW);
    int*    idx_ws   = (int*)(ws + OFF_IDX);
    int*    histb    = (int*)(ws + OFF_HISTB);
    int*    sorted   = (int*)(ws + OFF_SORT);
    int*    flaglist = (int*)(ws + OFF_FLAGS);
    short*  wfrag    = (short*)(ws + OFF_WFRAG);

    float* xt        = out + 1;               // scratch: overwritten by out_kernel
    float* out_idx_f = out + 1 + (size_t)N_ELEM;

    hipMemsetAsync(ws, 0, ZERO_BYTES, stream);  // loss + flagcnt only

    prep_kernel<<<36, 256, 0, stream>>>(weight, wfrag, w2f, w2d);

    argmin_kernel<<<N_ROWS / 64, 256, 0, stream>>>(
        inp, wfrag, w2f, idx_ws, out_idx_f, xt, flagcnt, flaglist);

    refine_kernel<<<1024, 256, 0, stream>>>(
        xt, weight, w2d, idx_ws, out_idx_f, flagcnt, flaglist);

    hist_kernel<<<NHB, 256, 0, stream>>>(idx_ws, histb);

    scan_kernel<<<1, 1024, 0, stream>>>(histb, goff, ema_cs, csbuf);

    scatter_kernel<<<NHB, 256, 0, stream>>>(idx_ws, histb, sorted);

    dwred_kernel<<<K_CODES, 256, 0, stream>>>(xt, sorted, goff, dw);

    emaw_kernel<<<K_CODES * D_DIM / 256, 256, 0, stream>>>(ema_w, dw, csbuf, new_w);

    out_kernel<<<N_ROWS / 256, 256, 0, stream>>>(inp, new_w, idx_ws, out, loss_acc);

    loss_final<<<1, 1, 0, stream>>>(loss_acc, out);
}